// Round 4
// baseline (460.510 us; speedup 1.0000x reference)
//
#include <hip/hip_runtime.h>

// LengthRegulator, round 4: fill-shaped linear sweep with precomputed
// row->source table. Decisive A/B vs hypothesis that all prior structures
// shared an MLP/sweep-shape defect vs fillBufferAligned (6.3 TB/s).
//
// Kernel A (32 blocks x 256 thr): per-batch csum of duration; writes
//   g_srcoff[b*T + t] = premultiplied global x vec4-offset for output row t
//   (or -1 for masked tail rows), plus mel_out[b]. ~1 MB table, ~3 us.
// Kernel B (4096 blocks x 256 thr): flat linear sweep of all 25.2M f32x4
//   output elements, 24 iters/thread, unroll 4. Per element: table lookup
//   (L1-broadcast, 64 lanes share 1-2 entries), conditional 16B x load
//   (L1-temporal reuse: duplicated rows are adjacent in sweep), 16B store
//   in exactly the fill's linear order. No LDS, no barriers.

#define BATCH 32
#define SRC_S 1024
#define DIM   384
#define C4    (DIM / 4)      // 96 f32x4 per row
#define TMAX  8192
#define NROW  (BATCH * TMAX) // 262144 output rows

typedef float f32x4 __attribute__((ext_vector_type(4)));
typedef int   i32x4 __attribute__((ext_vector_type(4)));

__device__ int g_srcoff[NROW];   // per output row: global x vec4 offset, or -1

// ---------------- Kernel A: csum + row->src table + mel_len ----------------
__global__ __launch_bounds__(256)
void lr_table_kernel(const int* __restrict__ duration, float* __restrict__ mel_out,
                     int T) {
    __shared__ int wsum[4];
    const int b = blockIdx.x;
    const int tid = threadIdx.x;
    const int lane = tid & 63;
    const int wid = tid >> 6;

    const i32x4 d = ((const i32x4*)(duration + b * SRC_S))[tid];
    const int s0 = d.x;
    const int s1 = s0 + d.y;
    const int s2 = s1 + d.z;
    const int s3 = s2 + d.w;               // thread-local inclusive sums
    int tot = s3;
    #pragma unroll
    for (int off = 1; off < 64; off <<= 1) {   // wave inclusive scan
        const int n = __shfl_up(tot, off, 64);
        if (lane >= off) tot += n;
    }
    if (lane == 63) wsum[wid] = tot;
    __syncthreads();
    int base = 0;
    #pragma unroll
    for (int w = 0; w < 3; ++w) base += (w < wid) ? wsum[w] : 0;
    const int mel = wsum[0] + wsum[1] + wsum[2] + wsum[3];
    const int pre = base + tot - s3;       // thread's exclusive prefix

    int* __restrict__ tb = g_srcoff + b * T;
    const int xbase = b * SRC_S * C4;      // premultiplied global x offset base
    const int st[4] = {pre, pre + s0, pre + s1, pre + s2};
    const int en[4] = {pre + s0, pre + s1, pre + s2, pre + s3};
    #pragma unroll
    for (int e = 0; e < 4; ++e) {
        const int off = xbase + (tid * 4 + e) * C4;
        for (int t = st[e]; t < en[e]; ++t) tb[t] = off;   // run-scatter
    }
    for (int t = mel + tid; t < T; t += 256) tb[t] = -1;   // masked tail

    if (tid == 0) mel_out[b] = (float)mel;  // exact in f32 (<= 7168)
}

// ---------------- Kernel B: fill-shaped gather sweep ----------------
__global__ __launch_bounds__(256)
void lr_sweep_kernel(const f32x4* __restrict__ x4, f32x4* __restrict__ out4,
                     int iters) {
    const int tid = threadIdx.x;
    const int base = blockIdx.x * (iters * 256) + tid;  // contiguous block chunk

    #pragma unroll 4
    for (int k = 0; k < iters; ++k) {
        const int i = base + k * 256;                // < 25.2M, fits i32
        const int row = i / C4;                      // magic mul
        const int col = i - row * C4;
        const int o = g_srcoff[row];                 // L1-broadcast (1-2/wave)
        f32x4 v = (f32x4)(0.f);
        if (o >= 0) v = x4[o + col];                 // L1-temporal x reuse
        out4[i] = v;                                 // linear store order
    }
}

extern "C" void kernel_launch(void* const* d_in, const int* in_sizes, int n_in,
                              void* d_out, int out_size, void* d_ws, size_t ws_size,
                              hipStream_t stream) {
    const float* x = (const float*)d_in[0];
    const int* duration = (const int*)d_in[1];
    const int T = (out_size - BATCH) / (BATCH * DIM);   // 8192

    float* out = (float*)d_out;
    float* mel_out = out + (size_t)BATCH * T * DIM;     // out1 region

    lr_table_kernel<<<BATCH, 256, 0, stream>>>(duration, mel_out, T);

    const int total = BATCH * T * C4;                   // 25,165,824 vec4
    const int iters = 24;
    const int nblocks = total / (iters * 256);          // 4096
    lr_sweep_kernel<<<nblocks, 256, 0, stream>>>((const f32x4*)x,
                                                 (f32x4*)out, iters);
}